// Round 12
// baseline (89.866 us; speedup 1.0000x reference)
//
#include <hip/hip_runtime.h>
#include <hip/hip_bf16.h>
#include <math.h>

// DistWeightLoss on MI355X — round 12: symmetric triangular tiles (r8 logic,
// absmax 0 verified) re-done in the PROVEN codegen regime: 512-thread blocks
// + __launch_bounds__(512,2) (r3/r4/r6: ~116 VGPR, no spill; 256/1024-thr
// blocks get squeezed to 48-64 VGPR and remat/spill — r5/r8/r10/r11).
// Halves every pipe term vs r6 (MFMA/LDS/L2/VALU).
//
// ws layout: [0:N) pos_min f32 | [N:2N) row_sum f32 | [2N:3N) row_cnt f32
//            | [3N:) Xbf bf16 [N][D]
//   A) pos_kernel: per-class 8x8 Gram (fp32, exact) + fused cvt + zero-init;
//      gumbel tail parallelized across 56 lanes (8 rows x 7 candidates).
//   B) neg_sym_kernel: 2080 blocks (upper-tri 128x128 tiles), 512 thr =
//      8 waves (4wr x 2wc), wave = 32 rows x 64 cols, acc[2][4].
//      B tile staged once in LDS (32 KB, swizzled); A rows direct to regs.
//      Off-diag: dual-sided (row thr[i] + col thr[j]) accumulation;
//      diag: row-side only + class check. Shfl-reduce + atomics.
//   C) finalize_kernel: loss = sum(valid? s/c - pos + m : 0)/N.

#define NN 8192
#define DD 128
#define KK 8
#define MARGIN 0.01f
#define NBI 64           // 8192/128 tiles per side

typedef __attribute__((ext_vector_type(8))) short short8;
typedef __attribute__((ext_vector_type(4))) float f32x4;

// ---------------- Threefry2x32 / JAX gumbel (bit-exact, validated) ----------------
__device__ __forceinline__ unsigned rotl32(unsigned x, unsigned r) {
    return (x << r) | (x >> (32u - r));
}

__device__ float gumbel_at(unsigned m) {
    const unsigned HALF = (NN * (KK - 1)) / 2;  // 28672
    unsigned c   = (m < HALF) ? m : (m - HALF);
    bool     hi  = (m >= HALF);
    const unsigned ks0 = 0u, ks1 = 42u;
    const unsigned ks2 = 0x1BD11BDAu ^ ks0 ^ ks1;
    unsigned x0 = c + ks0;
    unsigned x1 = (c + HALF) + ks1;
#define TF_ROUND(r) { x0 += x1; x1 = rotl32(x1, (r)); x1 ^= x0; }
    TF_ROUND(13) TF_ROUND(15) TF_ROUND(26) TF_ROUND(6)
    x0 += ks1; x1 += ks2 + 1u;
    TF_ROUND(17) TF_ROUND(29) TF_ROUND(16) TF_ROUND(24)
    x0 += ks2; x1 += ks0 + 2u;
    TF_ROUND(13) TF_ROUND(15) TF_ROUND(26) TF_ROUND(6)
    x0 += ks0; x1 += ks1 + 3u;
    TF_ROUND(17) TF_ROUND(29) TF_ROUND(16) TF_ROUND(24)
    x0 += ks1; x1 += ks2 + 4u;
    TF_ROUND(13) TF_ROUND(15) TF_ROUND(26) TF_ROUND(6)
    x0 += ks2; x1 += ks0 + 5u;
#undef TF_ROUND
    unsigned bits = hi ? x1 : x0;
    float f = __uint_as_float((bits >> 9) | 0x3f800000u) - 1.0f;
    float u = fmaxf(f, 1.17549435e-38f);
    return -logf(-logf(u));
}

// ---------------- fp32 -> bf16 (RNE) ----------------
__device__ __forceinline__ unsigned short bf16r(float f) {
    unsigned u = __float_as_uint(f);
    unsigned r = (u + 0x7FFFu + ((u >> 16) & 1u)) >> 16;
    return (unsigned short)r;
}

// ---------------- Kernel A: pos_min + cvt + zero-init (parallel gumbel tail) --------
__global__ __launch_bounds__(64) void pos_kernel(const float* __restrict__ X,
                                                 float* __restrict__ pos_min,
                                                 float* __restrict__ row_sum,
                                                 float* __restrict__ row_cnt,
                                                 unsigned short* __restrict__ Xbf) {
    __shared__ float Xc[KK * DD];
    __shared__ float gram[KK * KK];
    __shared__ float pss[KK][KK - 1];   // sorted positives per row
    __shared__ float scr[KK][KK - 1];   // gumbel-perturbed scores
    const int c   = blockIdx.x;
    const int tid = threadIdx.x;

    if (tid < KK) {
        row_sum[c * KK + tid] = 0.f;
        row_cnt[c * KK + tid] = 0.f;
    }

    const float4* src = (const float4*)(X + (size_t)c * KK * DD);
    float4*       dst = (float4*)Xc;
#pragma unroll
    for (int it = 0; it < (KK * DD / 4) / 64; ++it)
        dst[tid + it * 64] = src[tid + it * 64];
    __syncthreads();

    ushort4* obf = (ushort4*)(Xbf + (size_t)c * KK * DD);
#pragma unroll
    for (int it = 0; it < 4; ++it) {
        int idx = tid + it * 64;
        float4 v = ((const float4*)Xc)[idx];
        ushort4 o;
        o.x = bf16r(v.x); o.y = bf16r(v.y); o.z = bf16r(v.z); o.w = bf16r(v.w);
        obf[idx] = o;
    }

    const int a = tid >> 3, b = tid & 7;
    float s = 0.f;
#pragma unroll
    for (int k = 0; k < DD; k += 4) {
        float4 va = *(const float4*)&Xc[a * DD + k];
        float4 vb = *(const float4*)&Xc[b * DD + k];
        s += va.x * vb.x + va.y * vb.y + va.z * vb.z + va.w * vb.w;
    }
    gram[a * KK + b] = s;
    __syncthreads();

    // 8 lanes: gather + sort positives, publish to LDS
    if (tid < KK) {
        const int r = tid;
        float ps[KK - 1];
#pragma unroll
        for (int jj = 0; jj < KK - 1; ++jj)
            ps[jj] = gram[r * KK + ((r + 1 + jj) & (KK - 1))];
#pragma unroll
        for (int p = 0; p < KK - 2; ++p)
#pragma unroll
            for (int q = 0; q < KK - 2 - p; ++q) {
                float lo = fminf(ps[q], ps[q + 1]);
                float hi = fmaxf(ps[q], ps[q + 1]);
                ps[q] = lo; ps[q + 1] = hi;
            }
#pragma unroll
        for (int jj = 0; jj < KK - 1; ++jj) pss[r][jj] = ps[jj];
    }
    __syncthreads();

    // 56 lanes: one gumbel each
    if (tid < KK * (KK - 1)) {
        const int r  = tid / (KK - 1);
        const int jj = tid % (KK - 1);
        const int i  = c * KK + r;
        float g = gumbel_at((unsigned)(i * (KK - 1) + jj));
        scr[r][jj] = 5.0f * pss[r][jj] + g;
    }
    __syncthreads();

    // 8 lanes: first-max argmax (matches jax argmax tie semantics)
    if (tid < KK) {
        const int r = tid;
        float best = scr[r][0];
        float pmin = pss[r][0];
#pragma unroll
        for (int jj = 1; jj < KK - 1; ++jj) {
            if (scr[r][jj] > best) { best = scr[r][jj]; pmin = pss[r][jj]; }
        }
        pos_min[c * KK + r] = pmin;
    }
}

// ---------------- async global->LDS 16B ----------------
__device__ __forceinline__ void async16(const void* g, void* l) {
    __builtin_amdgcn_global_load_lds(
        (const __attribute__((address_space(1))) unsigned int*)g,
        (__attribute__((address_space(3))) unsigned int*)l, 16, 0, 0);
}

// ---------------- Kernel B: symmetric 128x128 tile, 8 waves, dual-sided ----------------
// B LDS rows = 128 bf16 = 256 B = 16 chunks of 16B. ds_read swizzle:
// byte ^= ((row&7)<<4); global_load_lds writes linearly so the SOURCE
// chunk index carries the same involution (rule #21).
__global__ __launch_bounds__(512, 2) void neg_sym_kernel(const unsigned short* __restrict__ Xbf,
                                                         const float* __restrict__ pos_min,
                                                         float* __restrict__ row_sum,
                                                         float* __restrict__ row_cnt) {
    __shared__ unsigned short Bs[128 * DD];  // 32 KB
    const int tid  = threadIdx.x;
    const int lane = tid & 63;
    const int w    = tid >> 6;      // 0..7
    const int wr   = w >> 1;        // 0..3 : 32-row band
    const int wc   = w & 1;         // 0..1 : 64-col band
    const int l15  = lane & 15, l4 = lane >> 4;

    // triangular decode: blockIdx.x -> (bi, bj), bj >= bi  (r8-verified)
    const int id = blockIdx.x;
    int bi = (int)(0.5f * (129.0f - sqrtf(16641.0f - 8.0f * (float)id)));
    if (bi < 0) bi = 0; if (bi > NBI - 1) bi = NBI - 1;
    while (bi * (129 - bi) / 2 > id) --bi;
    while ((bi + 1) * (128 - bi) / 2 <= id) ++bi;
    const int bj = bi + (id - bi * (129 - bi) / 2);
    const int i0 = bi * 128, j0 = bj * 128;
    const bool diag = (bi == bj);

    // ---- stage B panel (rows j0..j0+127): 2048 chunks, 4 per thread
#pragma unroll
    for (int it = 0; it < 4; ++it) {
        int ch  = it * 512 + tid;
        int row = ch >> 4, c4 = ch & 15, srcc = c4 ^ (row & 7);
        async16(Xbf + (((size_t)(j0 + row)) << 7) + srcc * 8, &Bs[ch * 8]);
    }

    // ---- A fragments -> registers (wave's 32 rows)
    short8 areg[2][4];
#pragma unroll
    for (int m = 0; m < 2; ++m) {
        const int row = i0 + wr * 32 + m * 16 + l15;
#pragma unroll
        for (int kk = 0; kk < 4; ++kk)
            areg[m][kk] = *(const short8*)(Xbf + (((size_t)row) << 7) + kk * 32 + l4 * 8);
    }

    // row-side thresholds / class ids
    float thr[2][4];
    int   i3[2];
#pragma unroll
    for (int m = 0; m < 2; ++m) {
        const int ib = i0 + wr * 32 + m * 16 + l4 * 4;
        i3[m] = ib >> 3;
#pragma unroll
        for (int r = 0; r < 4; ++r) thr[m][r] = pos_min[ib + r] - MARGIN;
    }
    // col-side thresholds (lane's 4 columns within the wc band)
    float thrj[4];
#pragma unroll
    for (int n = 0; n < 4; ++n) thrj[n] = pos_min[j0 + wc * 64 + n * 16 + l15] - MARGIN;

    __syncthreads();  // B resident (barrier drains vmcnt)

    // ---- compute: wave = 32 rows x 64 cols; acc[2][4]
    f32x4 acc[2][4] = {};
#pragma unroll
    for (int kk = 0; kk < 4; ++kk) {
        const int kb = (kk * 32 + l4 * 8) * 2;
        short8 b[4];
#pragma unroll
        for (int n = 0; n < 4; ++n) {
            const int rb = wc * 64 + n * 16 + l15;
            b[n] = *(const short8*)((const char*)Bs + ((rb * 256 + kb) ^ ((rb & 7) << 4)));
        }
#pragma unroll
        for (int m = 0; m < 2; ++m)
#pragma unroll
            for (int n = 0; n < 4; ++n)
                acc[m][n] = __builtin_amdgcn_mfma_f32_16x16x32_bf16(areg[m][kk], b[n], acc[m][n], 0, 0, 0);
    }

    // ---- epilogue (C/D layout: col=lane&15, row=(lane>>4)*4+reg)
    float s[2][4] = {{0.f}}, c[2][4] = {{0.f}};
    if (diag) {
        // row-side only (tile holds both orders), with class exclusion
#pragma unroll
        for (int n = 0; n < 4; ++n) {
            const int j3 = (j0 + wc * 64 + n * 16 + l15) >> 3;
#pragma unroll
            for (int m = 0; m < 2; ++m)
#pragma unroll
                for (int r = 0; r < 4; ++r) {
                    float v = acc[m][n][r];
                    bool k = (v > thr[m][r]) && (i3[m] != j3);
                    s[m][r] += k ? v : 0.f;
                    c[m][r] += k ? 1.f : 0.f;
                }
        }
    } else {
        // dual-sided: row i (thr[i]) and col j (thr[j]); disjoint 128-tiles
        // never share a class -> no class check.
        float sc[4] = {0.f}, cc[4] = {0.f};
#pragma unroll
        for (int n = 0; n < 4; ++n) {
#pragma unroll
            for (int m = 0; m < 2; ++m)
#pragma unroll
                for (int r = 0; r < 4; ++r) {
                    float v = acc[m][n][r];
                    bool kr = (v > thr[m][r]);
                    s[m][r] += kr ? v : 0.f;
                    c[m][r] += kr ? 1.f : 0.f;
                    bool kc = (v > thrj[n]);
                    sc[n] += kc ? v : 0.f;
                    cc[n] += kc ? 1.f : 0.f;
                }
        }
        // col-side reduce over the 4 l4-quads, atomics from l4==0 lanes
#pragma unroll
        for (int n = 0; n < 4; ++n) {
            float sv = sc[n], cv = cc[n];
            sv += __shfl_xor(sv, 16); cv += __shfl_xor(cv, 16);
            sv += __shfl_xor(sv, 32); cv += __shfl_xor(cv, 32);
            if (l4 == 0) {
                int j = j0 + wc * 64 + n * 16 + l15;
                atomicAdd(&row_sum[j], sv);
                atomicAdd(&row_cnt[j], cv);
            }
        }
    }

    // row-side reduce across the 16 col-lanes, then atomics
#pragma unroll
    for (int m = 0; m < 2; ++m)
#pragma unroll
        for (int r = 0; r < 4; ++r) {
            float sv = s[m][r], cv = c[m][r];
#pragma unroll
            for (int off = 1; off < 16; off <<= 1) {
                sv += __shfl_xor(sv, off);
                cv += __shfl_xor(cv, off);
            }
            if (l15 == 0) {
                int i = i0 + wr * 32 + m * 16 + l4 * 4 + r;
                atomicAdd(&row_sum[i], sv);
                atomicAdd(&row_cnt[i], cv);
            }
        }
}

// ---------------- Kernel C: finalize ----------------
__global__ __launch_bounds__(1024) void finalize_kernel(const float* __restrict__ row_sum,
                                                        const float* __restrict__ row_cnt,
                                                        const float* __restrict__ pos_min,
                                                        float* __restrict__ out) {
    __shared__ float red[1024];
    const int tid = threadIdx.x;
    float local = 0.f;
#pragma unroll
    for (int it = 0; it < NN / 1024; ++it) {
        int i = tid + it * 1024;
        float cnt = row_cnt[i];
        if (cnt > 0.f) {
            float nm = row_sum[i] / fmaxf(cnt, 1.0f);
            local += nm - pos_min[i] + MARGIN;
        }
    }
    red[tid] = local;
    __syncthreads();
    for (int st = 512; st > 0; st >>= 1) {
        if (tid < st) red[tid] += red[tid + st];
        __syncthreads();
    }
    if (tid == 0) out[0] = red[0] / (float)NN;
}

extern "C" void kernel_launch(void* const* d_in, const int* in_sizes, int n_in,
                              void* d_out, int out_size, void* d_ws, size_t ws_size,
                              hipStream_t stream) {
    const float* X = (const float*)d_in[0];
    float* pos_min = (float*)d_ws;
    float* row_sum = pos_min + NN;
    float* row_cnt = row_sum + NN;
    unsigned short* Xbf = (unsigned short*)((char*)d_ws + (size_t)3 * NN * 4);

    pos_kernel<<<NN / KK, 64, 0, stream>>>(X, pos_min, row_sum, row_cnt, Xbf);
    const int nblk = NBI * (NBI + 1) / 2;  // 2080
    neg_sym_kernel<<<nblk, 512, 0, stream>>>(Xbf, pos_min, row_sum, row_cnt);
    finalize_kernel<<<1, 1024, 0, stream>>>(row_sum, row_cnt, pos_min, (float*)d_out);
}